// Round 13
// baseline (231.270 us; speedup 1.0000x reference)
//
#include <hip/hip_runtime.h>
#include <math.h>

#define IS3 0.57735026918962576f   // 1/sqrt(3)
#define IS6 0.40824829046386302f   // 1/sqrt(6)

#define SHIFT 11                   // 2048 nodes per bucket
#define BSZ   2048
#define CAP   36864u               // slots per bucket (mean 32653, +23 sigma)
#define MQ    4096.0f              // message quantization scale (i16)
#define IMQ   (1.0f/4096.0f)

typedef float v2f __attribute__((ext_vector_type(2)));

__device__ __forceinline__ float fastrcp(float x) { return __builtin_amdgcn_rcpf(x); }
__device__ __forceinline__ v2f mk2(float a, float b) { v2f r; r.x = a; r.y = b; return r; }

// T(x) = tanh(w2 * tanh(w1*x)), 2 channels at once (R5-proven packed form).
__device__ __forceinline__ v2f Tnl2(v2f x, v2f tw1, v2f w2) {
    v2f t = tw1 * x;
    v2f e;
    e.x = __expf(t.x);
    e.y = __expf(t.y);
    v2f ep = e + 1.0f;
    v2f r;
    r.x = fastrcp(ep.x);
    r.y = fastrcp(ep.y);
    v2f u = 1.0f - 2.0f * r;                 // tanh(w1*x)
    v2f z = w2 * u;
    v2f z2 = z * z;
    v2f p = z2 * 0.133333333f - 0.333333333f;
    return z * z2 * p + z;
}

__device__ __forceinline__ int q16(float x) {
    int v = (int)rintf(x * MQ);
    v = v >  32767 ?  32767 : v;
    v = v < -32768 ? -32768 : v;
    return v;
}

// ---- K1: fused message compute + bucket routing. EXACT R7 form (best
// verified, 53us). R10: 1024-thr blocks are load-bearing for scatter
// coalescing. R11: no cross-block fusion (fence traffic). Do not touch.
__global__ __launch_bounds__(1024, 8) void route_kernel(
    const int* __restrict__ ei, const float* __restrict__ f,
    const float* __restrict__ d, const float* __restrict__ a,
    const float* __restrict__ w1p, const float* __restrict__ w2p,
    unsigned* __restrict__ tails,        // [nbuk*64] padded, pre-zeroed
    unsigned* __restrict__ qmeta,        // [nbuk*CAP]
    uint2* __restrict__ qmsg,            // [nbuk*CAP]
    int E, int nbuk)
{
    __shared__ unsigned hcnt[64];
    __shared__ unsigned hoff[64];
    int tid = threadIdx.x;
    if (tid < 64) hcnt[tid] = 0;

    int e = blockIdx.x * 1024 + tid;
    bool valid = (e < E);

    float tw10 = 2.0f * w1p[0], tw11 = 2.0f * w1p[1];
    float w20 = w2p[0], w21 = w2p[1];

    // prefetch phase: issue every global load before barrier #1
    int t = 0, s = 0;
    float4 sA = make_float4(0.f,0.f,0.f,0.f), sB = sA, tA = sA, tB = sA, av = sA;
    float de = 0.f;
    if (valid) {
        t = ei[E + e];
        s = ei[e];
        const float4* f4 = (const float4*)f;
        sA = f4[2*s]; sB = f4[2*s+1];
        tA = f4[2*t]; tB = f4[2*t+1];
        de = d[e];
        av = ((const float4*)a)[e];
    }

    __syncthreads();                     // #1: hcnt init visible

    unsigned b = 0, lrank = 0;
    if (valid) {
        b = (((unsigned)t) >> SHIFT) & 63u;   // mask = defensive no-op for N=100000
        lrank = atomicAdd(&hcnt[b], 1u);      // LDS int atomic (native)
    }
    __syncthreads();                     // #2: counts final

    unsigned basek = 0;
    if (tid < nbuk && hcnt[tid] != 0u)
        basek = atomicAdd(&tails[tid * 64], hcnt[tid]);  // hidden under compute

    unsigned dq = 0;
    uint2 pk = make_uint2(0u, 0u);
    if (valid) {
        float a0 = av.x, ax = av.y, ay = av.z, az = av.w;
        float axs = ax * IS3, ays = ay * IS3, azs = az * IS3;
        float a03 = a0 * IS3;

        v2f twSX = mk2(tw10, tw11), w2SX = mk2(w20, w21);
        v2f twXY = mk2(tw11, tw11), w2XY = mk2(w21, w21);
        v2f twCX = mk2(tw11, tw10), w2CX = mk2(w21, w20);
        v2f twDD = mk2(tw10, tw10), w2DD = mk2(w20, w20);

        v2f aSX = mk2(a0, axs);
        v2f aYZ = mk2(ays, azs);

        float sc[5] = { sA.x, sA.y, tA.x, tA.y, de };
        float vx[4] = { sA.z, sB.y, tA.z, tB.y };
        float vy[4] = { sA.w, sB.z, tA.w, tB.z };
        float vz[4] = { sB.x, sB.w, tB.x, tB.w };

        v2f mSX = mk2(0.f, 0.f);
        v2f mYZ = mk2(0.f, 0.f);
        float cz6[4];

        #pragma unroll
        for (int i = 0; i < 5; ++i) {
            mSX += Tnl2(sc[i] * aSX, twSX, w2SX);
            mYZ += Tnl2(sc[i] * aYZ, twXY, w2XY);
        }
        #pragma unroll
        for (int i = 0; i < 4; ++i) {
            float dva = vx[i]*ax + vy[i]*ay + vz[i]*az;
            mSX += Tnl2(mk2(dva * IS3, vx[i] * a03), twCX, w2CX);
            mYZ += Tnl2(mk2(vy[i] * a03, vz[i] * a03), twDD, w2DD);
            float cx = vy[i]*az - vz[i]*ay;
            float cy = vz[i]*ax - vx[i]*az;
            float cz = vx[i]*ay - vy[i]*ax;
            v2f exy = Tnl2(mk2(cx * IS6, cy * IS6), twXY, w2XY);
            mSX.y += exy.x;
            mYZ.x += exy.y;
            cz6[i] = cz * IS6;
        }
        v2f g1 = Tnl2(mk2(cz6[0], cz6[1]), twXY, w2XY);
        v2f g2 = Tnl2(mk2(cz6[2], cz6[3]), twXY, w2XY);
        mYZ.y += (g1.x + g1.y) + (g2.x + g2.y);

        unsigned dqi = (unsigned)(de * 2047.0f + 0.5f);
        dq = dqi > 2047u ? 2047u : dqi;
        int qS = q16(mSX.x), qX = q16(mSX.y), qY = q16(mYZ.x), qZ = q16(mYZ.y);
        pk.x = ((unsigned)(unsigned short)qS) | (((unsigned)(unsigned short)qX) << 16);
        pk.y = ((unsigned)(unsigned short)qY) | (((unsigned)(unsigned short)qZ) << 16);
    }

    if (tid < nbuk) hoff[tid] = basek;   // s_waitcnt lands here, post-compute
    __syncthreads();                     // #3

    if (valid) {
        unsigned pos = hoff[b] + lrank;
        if (pos < CAP) {                 // safety clamp; never hit
            size_t idx = (size_t)b * CAP + pos;
            qmeta[idx] = (((unsigned)(t & (BSZ - 1))) << 11) | dq;
            qmsg[idx]  = pk;
        }
    }
}

// ---- K2: one workgroup per (bucket, segment). EXACT R7 form.
__global__ __launch_bounds__(1024) void bucket_kernel(
    const unsigned* __restrict__ tails, const unsigned* __restrict__ qmeta,
    const uint2* __restrict__ qmsg, unsigned* __restrict__ partial,
    int nbuk, int seg)
{
    __shared__ unsigned long long accSX[BSZ];   // 16KB
    __shared__ unsigned long long accYZ[BSZ];   // 16KB
    __shared__ unsigned accM[BSZ];              // 8KB
    int wg = blockIdx.x;
    int b = wg / seg, sgi = wg % seg;
    for (int i = threadIdx.x; i < BSZ; i += 1024) {
        accSX[i] = 0ull; accYZ[i] = 0ull; accM[i] = 0u;
    }
    __syncthreads();

    unsigned tail = tails[b * 64];
    if (tail > CAP) tail = CAP;
    unsigned lo = (unsigned)(((unsigned long long)tail * sgi) / seg);
    unsigned hi = (unsigned)(((unsigned long long)tail * (sgi + 1)) / seg);
    size_t base = (size_t)b * CAP;

    for (unsigned q = lo + threadIdx.x; q < hi; q += 1024) {
        unsigned meta = qmeta[base + q];
        uint2 m = qmsg[base + q];
        int local = (int)(meta >> 11);
        int qS = (int)(short)(m.x & 0xFFFFu);
        int qX = (int)(short)(m.x >> 16);
        int qY = (int)(short)(m.y & 0xFFFFu);
        int qZ = (int)(short)(m.y >> 16);
        unsigned long long vSX =
            (((unsigned long long)(unsigned)qX) << 32) | (unsigned)(qS + 65536);
        unsigned long long vYZ =
            (((unsigned long long)(unsigned)qZ) << 32) | (unsigned)(qY + 65536);
        atomicAdd(&accSX[local], vSX);
        atomicAdd(&accYZ[local], vYZ);
        atomicAdd(&accM[local], (1u << 20) | (meta & 2047u));
    }
    __syncthreads();

    unsigned* dst = partial + (size_t)wg * (BSZ * 5);
    for (int i = threadIdx.x; i < BSZ; i += 1024) {
        unsigned long long sx = accSX[i], yz = accYZ[i];
        dst[0*BSZ + i] = (unsigned)sx;
        dst[1*BSZ + i] = (unsigned)(sx >> 32);
        dst[2*BSZ + i] = (unsigned)yz;
        dst[3*BSZ + i] = (unsigned)(yz >> 32);
        dst[4*BSZ + i] = accM[i];
    }
}

// ---- K3 (R13): R12 scalar-path mlp with the spill fixed.
// R12 evidence: __launch_bounds__(256,8) capped VGPR at 64 < ~90 live set
// -> scratch spill (WRITE_SIZE 3.1->27.9MB, VGPR=32, 64.6us). The scalar
// promotion itself worked (SGPR=80, LDS=0). (256,4) caps at 128 VGPR:
// no spill, still 16 waves/CU.
template<int SEGC>
__global__ __launch_bounds__(256, 4) void mlp_kernel(
    const float* __restrict__ f, const unsigned* __restrict__ partial,
    const float* __restrict__ W0, const float* __restrict__ b0,
    const float* __restrict__ W1, const float* __restrict__ b1,
    const float* __restrict__ W2, const float* __restrict__ b2,
    float* __restrict__ out, int N)
{
    int tid = threadIdx.x;
    int n = blockIdx.x * 256 + tid;
    bool vn = (n < N);
    int nc = vn ? n : (N - 1);          // clamped: loads stay in-bounds

    // ---- issue ALL per-node global loads first (fully unrolled,
    // independent); their latency hides under the first weight tiles.
    int b = nc >> SHIFT;
    int local = nc & (BSZ - 1);
    unsigned pl[SEGC][5];
    #pragma unroll
    for (int s2 = 0; s2 < SEGC; ++s2) {
        const unsigned* p = partial + ((size_t)(b * SEGC + s2)) * (BSZ * 5);
        pl[s2][0] = p[0*BSZ + local];
        pl[s2][1] = p[1*BSZ + local];
        pl[s2][2] = p[2*BSZ + local];
        pl[s2][3] = p[3*BSZ + local];
        pl[s2][4] = p[4*BSZ + local];
    }
    float4 fA = ((const float4*)f)[2*nc];
    float4 fB = ((const float4*)f)[2*nc+1];

    int S = 0, X = 0, Y = 0, Z = 0, cnt = 0, dqs = 0;
    #pragma unroll
    for (int s2 = 0; s2 < SEGC; ++s2) {
        unsigned m4 = pl[s2][4];
        int c = (int)(m4 >> 20);
        S += (int)pl[s2][0] - (c << 16);
        X += (int)pl[s2][1];
        Y += (int)pl[s2][2] - (c << 16);
        Z += (int)pl[s2][3];
        dqs += (int)(m4 & 0xFFFFFu);
        cnt += c;
    }
    float aS = (float)S * IMQ, ax = (float)X * IMQ;
    float ay = (float)Y * IMQ, az = (float)Z * IMQ;
    float cf = (float)cnt;
    float dsum = (float)dqs * (1.0f / 2047.0f);

    float nrm1 = sqrtf(fA.z*fA.z + fA.w*fA.w + fB.x*fB.x);
    float nrm2 = sqrtf(fB.y*fB.y + fB.z*fB.z + fB.w*fB.w);
    float nv   = sqrtf(ax*ax + ay*ay + az*az);
    float avgd = dsum * fastrcp(cf + 1e-8f);
    float pk9[9] = { fA.x, fA.y, nrm1, nrm2, aS, aS, nv, nv, avgd };

    // uniform-address weight views (scalar-promotable)
    const float4* W0v = (const float4*)W0;   // [9][64] row-major -> 9*16 float4
    const float4* b0v = (const float4*)b0;   // 16
    const float4* W1v = (const float4*)W1;   // [64][32] -> 64*8
    const float4* b1v = (const float4*)b1;   // 8
    const float4* W2v = (const float4*)W2;   // [32][4] -> 32
    const float4* b2v = (const float4*)b2;   // 1

    float x1s[32];
    #pragma unroll
    for (int j = 0; j < 8; ++j) {
        float4 bv = b1v[j];
        x1s[4*j+0] = bv.x; x1s[4*j+1] = bv.y; x1s[4*j+2] = bv.z; x1s[4*j+3] = bv.w;
    }

    // layer1 (tiled 8 hidden units) + layer2 interleaved
    #pragma unroll
    for (int tile = 0; tile < 8; ++tile) {
        float h[8];
        {
            float4 ba = b0v[2*tile], bb = b0v[2*tile+1];
            h[0]=ba.x; h[1]=ba.y; h[2]=ba.z; h[3]=ba.w;
            h[4]=bb.x; h[5]=bb.y; h[6]=bb.z; h[7]=bb.w;
        }
        #pragma unroll
        for (int k = 0; k < 9; ++k) {
            float4 wa = W0v[k*16 + 2*tile];
            float4 wb = W0v[k*16 + 2*tile + 1];
            float pv = pk9[k];
            h[0] += pv*wa.x; h[1] += pv*wa.y; h[2] += pv*wa.z; h[3] += pv*wa.w;
            h[4] += pv*wb.x; h[5] += pv*wb.y; h[6] += pv*wb.z; h[7] += pv*wb.w;
        }
        #pragma unroll
        for (int u = 0; u < 8; ++u) {
            float acc = fmaxf(h[u], 0.f);
            int i = 8*tile + u;
            #pragma unroll
            for (int j = 0; j < 8; ++j) {
                float4 wv = W1v[i*8+j];
                x1s[4*j+0] += acc * wv.x;
                x1s[4*j+1] += acc * wv.y;
                x1s[4*j+2] += acc * wv.z;
                x1s[4*j+3] += acc * wv.w;
            }
        }
    }
    #pragma unroll
    for (int j = 0; j < 32; ++j) x1s[j] = fmaxf(x1s[j], 0.f);

    float4 gb = b2v[0];
    float g0 = gb.x, g1 = gb.y, g2 = gb.z, g3 = gb.w;
    #pragma unroll
    for (int i = 0; i < 32; ++i) {
        float4 wv = W2v[i];
        g0 += x1s[i] * wv.x;
        g1 += x1s[i] * wv.y;
        g2 += x1s[i] * wv.z;
        g3 += x1s[i] * wv.w;
    }
    if (!vn) return;
    g0 = fastrcp(1.0f + __expf(-g0));
    g1 = fastrcp(1.0f + __expf(-g1));
    g2 = fastrcp(1.0f + __expf(-g2));
    g3 = fastrcp(1.0f + __expf(-g3));

    float* o = out + (size_t)8*n;
    o[0] = fA.x + g0*aS;
    o[1] = fA.y + g1*aS;
    o[2] = fA.z + g2*ax;
    o[3] = fA.w + g2*ay;
    o[4] = fB.x + g2*az;
    o[5] = fB.y + g3*ax;
    o[6] = fB.z + g3*ay;
    o[7] = fB.w + g3*az;
}

// generic fallback (runtime seg) -- only used if seg lands outside 1..10
__global__ __launch_bounds__(256) void mlp_kernel_gen(
    const float* __restrict__ f, const unsigned* __restrict__ partial,
    const float* __restrict__ W0, const float* __restrict__ b0,
    const float* __restrict__ W1, const float* __restrict__ b1,
    const float* __restrict__ W2, const float* __restrict__ b2,
    float* __restrict__ out, int N, int seg)
{
    int n = blockIdx.x * 256 + threadIdx.x;
    if (n >= N) return;

    int b = n >> SHIFT;
    int local = n & (BSZ - 1);
    int S = 0, X = 0, Y = 0, Z = 0, cnt = 0, dqs = 0;
    for (int s2 = 0; s2 < seg; ++s2) {
        const unsigned* p = partial + ((size_t)(b * seg + s2)) * (BSZ * 5);
        unsigned m4 = p[4*BSZ + local];
        int c = (int)(m4 >> 20);
        S += (int)p[0*BSZ + local] - (c << 16);
        X += (int)p[1*BSZ + local];
        Y += (int)p[2*BSZ + local] - (c << 16);
        Z += (int)p[3*BSZ + local];
        dqs += (int)(m4 & 0xFFFFFu);
        cnt += c;
    }
    float aS = (float)S * IMQ, ax = (float)X * IMQ;
    float ay = (float)Y * IMQ, az = (float)Z * IMQ;
    float dsum = (float)dqs * (1.0f / 2047.0f);

    float4 fA = ((const float4*)f)[2*n];
    float4 fB = ((const float4*)f)[2*n+1];

    float nrm1 = sqrtf(fA.z*fA.z + fA.w*fA.w + fB.x*fB.x);
    float nrm2 = sqrtf(fB.y*fB.y + fB.z*fB.z + fB.w*fB.w);
    float nv   = sqrtf(ax*ax + ay*ay + az*az);
    float avgd = dsum * fastrcp((float)cnt + 1e-8f);
    float pk9[9] = { fA.x, fA.y, nrm1, nrm2, aS, aS, nv, nv, avgd };

    float x1s[32];
    #pragma unroll
    for (int j = 0; j < 32; ++j) x1s[j] = b1[j];
    for (int i = 0; i < 64; ++i) {
        float acc = b0[i];
        #pragma unroll
        for (int k = 0; k < 9; ++k) acc += pk9[k] * W0[k*64 + i];
        acc = fmaxf(acc, 0.f);
        #pragma unroll
        for (int j = 0; j < 32; ++j) x1s[j] += acc * W1[i*32 + j];
    }
    #pragma unroll
    for (int j = 0; j < 32; ++j) x1s[j] = fmaxf(x1s[j], 0.f);

    float g0 = b2[0], g1 = b2[1], g2 = b2[2], g3 = b2[3];
    #pragma unroll
    for (int i = 0; i < 32; ++i) {
        g0 += x1s[i] * W2[i*4+0];
        g1 += x1s[i] * W2[i*4+1];
        g2 += x1s[i] * W2[i*4+2];
        g3 += x1s[i] * W2[i*4+3];
    }
    g0 = fastrcp(1.0f + __expf(-g0));
    g1 = fastrcp(1.0f + __expf(-g1));
    g2 = fastrcp(1.0f + __expf(-g2));
    g3 = fastrcp(1.0f + __expf(-g3));

    float* o = out + (size_t)8*n;
    o[0] = fA.x + g0*aS;
    o[1] = fA.y + g1*aS;
    o[2] = fA.z + g2*ax;
    o[3] = fA.w + g2*ay;
    o[4] = fB.x + g2*az;
    o[5] = fB.y + g3*ax;
    o[6] = fB.z + g3*ay;
    o[7] = fB.w + g3*az;
}

extern "C" void kernel_launch(void* const* d_in, const int* in_sizes, int n_in,
                              void* d_out, int out_size, void* d_ws, size_t ws_size,
                              hipStream_t stream) {
    const int*   ei = (const int*)d_in[0];
    const float* f  = (const float*)d_in[1];
    const float* d  = (const float*)d_in[2];
    const float* a  = (const float*)d_in[3];
    const float* w1 = (const float*)d_in[4];
    const float* w2 = (const float*)d_in[5];
    const float* W0 = (const float*)d_in[6];
    const float* b0 = (const float*)d_in[7];
    const float* W1 = (const float*)d_in[8];
    const float* b1 = (const float*)d_in[9];
    const float* W2 = (const float*)d_in[10];
    const float* b2 = (const float*)d_in[11];
    int E = in_sizes[0] / 2;
    int N = in_sizes[1] / 8;
    int nbuk = (N + BSZ - 1) >> SHIFT;          // 49 for N=100000

    // seg runtime-chosen: target grid = nbuk*seg ~ 512 (2 blocks/CU).
    size_t qn = (size_t)nbuk * CAP;
    size_t fixed = qn * 12 + (size_t)nbuk * 64 * 4;
    size_t per_seg = (size_t)nbuk * BSZ * 5 * 4;
    int segmax = nbuk > 0 ? (512 / nbuk) : 6;   // 10 for nbuk=49
    if (segmax < 1) segmax = 1;
    int seg = 6;
    if (ws_size > fixed + per_seg) {
        size_t m = (ws_size - fixed) / per_seg;
        seg = (int)(m < (size_t)segmax ? m : (size_t)segmax);
        if (seg < 1) seg = 1;
    }

    // workspace layout (bytes):
    //   qmsg    : nbuk*CAP*8        @ 0
    //   qmeta   : nbuk*CAP*4        @ qmsg_end
    //   partial : nbuk*seg*BSZ*5*4  @ qmeta_end
    //   tails   : nbuk*64*4         @ partial_end (zeroed)
    char* w = (char*)d_ws;
    uint2*    qmsg    = (uint2*)w;
    unsigned* qmeta   = (unsigned*)(w + qn * 8);
    unsigned* partial = (unsigned*)(w + qn * 12);
    unsigned* tails   = (unsigned*)(w + qn * 12 + (size_t)seg * per_seg);

    hipMemsetAsync(tails, 0, (size_t)nbuk * 64 * sizeof(unsigned), stream);

    int EB = (E + 1023) / 1024;     // 1563
    route_kernel <<<dim3(EB), dim3(1024), 0, stream>>>(
        ei, f, d, a, w1, w2, tails, qmeta, qmsg, E, nbuk);
    bucket_kernel<<<dim3(nbuk * seg), dim3(1024), 0, stream>>>(
        tails, qmeta, qmsg, partial, nbuk, seg);

    dim3 mg((N + 255) / 256), mb(256);
    switch (seg) {
      case 1:  mlp_kernel<1> <<<mg, mb, 0, stream>>>(f, partial, W0,b0,W1,b1,W2,b2, (float*)d_out, N); break;
      case 2:  mlp_kernel<2> <<<mg, mb, 0, stream>>>(f, partial, W0,b0,W1,b1,W2,b2, (float*)d_out, N); break;
      case 3:  mlp_kernel<3> <<<mg, mb, 0, stream>>>(f, partial, W0,b0,W1,b1,W2,b2, (float*)d_out, N); break;
      case 4:  mlp_kernel<4> <<<mg, mb, 0, stream>>>(f, partial, W0,b0,W1,b1,W2,b2, (float*)d_out, N); break;
      case 5:  mlp_kernel<5> <<<mg, mb, 0, stream>>>(f, partial, W0,b0,W1,b1,W2,b2, (float*)d_out, N); break;
      case 6:  mlp_kernel<6> <<<mg, mb, 0, stream>>>(f, partial, W0,b0,W1,b1,W2,b2, (float*)d_out, N); break;
      case 7:  mlp_kernel<7> <<<mg, mb, 0, stream>>>(f, partial, W0,b0,W1,b1,W2,b2, (float*)d_out, N); break;
      case 8:  mlp_kernel<8> <<<mg, mb, 0, stream>>>(f, partial, W0,b0,W1,b1,W2,b2, (float*)d_out, N); break;
      case 9:  mlp_kernel<9> <<<mg, mb, 0, stream>>>(f, partial, W0,b0,W1,b1,W2,b2, (float*)d_out, N); break;
      case 10: mlp_kernel<10><<<mg, mb, 0, stream>>>(f, partial, W0,b0,W1,b1,W2,b2, (float*)d_out, N); break;
      default:
        mlp_kernel_gen<<<mg, mb, 0, stream>>>(f, partial, W0,b0,W1,b1,W2,b2, (float*)d_out, N, seg);
    }
}

// Round 14
// 171.894 us; speedup vs baseline: 1.3454x; 1.3454x over previous
//
#include <hip/hip_runtime.h>
#include <math.h>

#define IS3 0.57735026918962576f   // 1/sqrt(3)
#define IS6 0.40824829046386302f   // 1/sqrt(6)

#define SHIFT 11                   // 2048 nodes per bucket
#define BSZ   2048
#define CAP   36864u               // slots per bucket (mean 32653, +23 sigma)
#define MQ    4096.0f              // message quantization scale (i16)
#define IMQ   (1.0f/4096.0f)

typedef float v2f __attribute__((ext_vector_type(2)));

__device__ __forceinline__ float fastrcp(float x) { return __builtin_amdgcn_rcpf(x); }
__device__ __forceinline__ v2f mk2(float a, float b) { v2f r; r.x = a; r.y = b; return r; }

// T(x) = tanh(w2 * tanh(w1*x)), 2 channels at once (R5-proven: packed
// v_pk_* halves VALU issue; exp/rcp co-issue on trans pipe).
__device__ __forceinline__ v2f Tnl2(v2f x, v2f tw1, v2f w2) {
    v2f t = tw1 * x;
    v2f e;
    e.x = __expf(t.x);
    e.y = __expf(t.y);
    v2f ep = e + 1.0f;
    v2f r;
    r.x = fastrcp(ep.x);
    r.y = fastrcp(ep.y);
    v2f u = 1.0f - 2.0f * r;                 // tanh(w1*x)
    v2f z = w2 * u;
    v2f z2 = z * z;
    v2f p = z2 * 0.133333333f - 0.333333333f;
    return z * z2 * p + z;
}

__device__ __forceinline__ int q16(float x) {
    int v = (int)rintf(x * MQ);
    v = v >  32767 ?  32767 : v;
    v = v < -32768 ? -32768 : v;
    return v;
}

// ---- K1: fused message compute + bucket routing (R2 structure, R5 packed
// math). Session-final form: 1024-thr blocks are load-bearing for scatter
// coalescing (R10); no global atomics (R9); no cross-block fusion (R11).
__global__ __launch_bounds__(1024, 8) void route_kernel(
    const int* __restrict__ ei, const float* __restrict__ f,
    const float* __restrict__ d, const float* __restrict__ a,
    const float* __restrict__ w1p, const float* __restrict__ w2p,
    unsigned* __restrict__ tails,        // [nbuk*64] padded, pre-zeroed
    unsigned* __restrict__ qmeta,        // [nbuk*CAP]
    uint2* __restrict__ qmsg,            // [nbuk*CAP]
    int E, int nbuk)
{
    __shared__ unsigned hcnt[64];
    __shared__ unsigned hoff[64];
    int tid = threadIdx.x;
    if (tid < 64) hcnt[tid] = 0;

    int e = blockIdx.x * 1024 + tid;
    bool valid = (e < E);

    float tw10 = 2.0f * w1p[0], tw11 = 2.0f * w1p[1];
    float w20 = w2p[0], w21 = w2p[1];

    // prefetch phase: issue every global load before barrier #1
    int t = 0, s = 0;
    float4 sA = make_float4(0.f,0.f,0.f,0.f), sB = sA, tA = sA, tB = sA, av = sA;
    float de = 0.f;
    if (valid) {
        t = ei[E + e];
        s = ei[e];
        const float4* f4 = (const float4*)f;
        sA = f4[2*s]; sB = f4[2*s+1];
        tA = f4[2*t]; tB = f4[2*t+1];
        de = d[e];
        av = ((const float4*)a)[e];
    }

    __syncthreads();                     // #1: hcnt init visible

    unsigned b = 0, lrank = 0;
    if (valid) {
        b = (((unsigned)t) >> SHIFT) & 63u;   // mask = defensive no-op for N=100000
        lrank = atomicAdd(&hcnt[b], 1u);      // LDS int atomic (native)
    }
    __syncthreads();                     // #2: counts final

    unsigned basek = 0;
    if (tid < nbuk && hcnt[tid] != 0u)
        basek = atomicAdd(&tails[tid * 64], hcnt[tid]);  // hidden under compute

    unsigned dq = 0;
    uint2 pk = make_uint2(0u, 0u);
    if (valid) {
        float a0 = av.x, ax = av.y, ay = av.z, az = av.w;
        float axs = ax * IS3, ays = ay * IS3, azs = az * IS3;
        float a03 = a0 * IS3;

        v2f twSX = mk2(tw10, tw11), w2SX = mk2(w20, w21);
        v2f twXY = mk2(tw11, tw11), w2XY = mk2(w21, w21);
        v2f twCX = mk2(tw11, tw10), w2CX = mk2(w21, w20);
        v2f twDD = mk2(tw10, tw10), w2DD = mk2(w20, w20);

        v2f aSX = mk2(a0, axs);
        v2f aYZ = mk2(ays, azs);

        float sc[5] = { sA.x, sA.y, tA.x, tA.y, de };
        float vx[4] = { sA.z, sB.y, tA.z, tB.y };
        float vy[4] = { sA.w, sB.z, tA.w, tB.z };
        float vz[4] = { sB.x, sB.w, tB.x, tB.w };

        v2f mSX = mk2(0.f, 0.f);
        v2f mYZ = mk2(0.f, 0.f);
        float cz6[4];

        #pragma unroll
        for (int i = 0; i < 5; ++i) {
            mSX += Tnl2(sc[i] * aSX, twSX, w2SX);
            mYZ += Tnl2(sc[i] * aYZ, twXY, w2XY);
        }
        #pragma unroll
        for (int i = 0; i < 4; ++i) {
            float dva = vx[i]*ax + vy[i]*ay + vz[i]*az;
            mSX += Tnl2(mk2(dva * IS3, vx[i] * a03), twCX, w2CX);
            mYZ += Tnl2(mk2(vy[i] * a03, vz[i] * a03), twDD, w2DD);
            float cx = vy[i]*az - vz[i]*ay;
            float cy = vz[i]*ax - vx[i]*az;
            float cz = vx[i]*ay - vy[i]*ax;
            v2f exy = Tnl2(mk2(cx * IS6, cy * IS6), twXY, w2XY);
            mSX.y += exy.x;
            mYZ.x += exy.y;
            cz6[i] = cz * IS6;
        }
        v2f g1 = Tnl2(mk2(cz6[0], cz6[1]), twXY, w2XY);
        v2f g2 = Tnl2(mk2(cz6[2], cz6[3]), twXY, w2XY);
        mYZ.y += (g1.x + g1.y) + (g2.x + g2.y);

        unsigned dqi = (unsigned)(de * 2047.0f + 0.5f);
        dq = dqi > 2047u ? 2047u : dqi;
        int qS = q16(mSX.x), qX = q16(mSX.y), qY = q16(mYZ.x), qZ = q16(mYZ.y);
        pk.x = ((unsigned)(unsigned short)qS) | (((unsigned)(unsigned short)qX) << 16);
        pk.y = ((unsigned)(unsigned short)qY) | (((unsigned)(unsigned short)qZ) << 16);
    }

    if (tid < nbuk) hoff[tid] = basek;   // s_waitcnt lands here, post-compute
    __syncthreads();                     // #3

    if (valid) {
        unsigned pos = hoff[b] + lrank;
        if (pos < CAP) {                 // safety clamp; never hit
            size_t idx = (size_t)b * CAP + pos;
            qmeta[idx] = (((unsigned)(t & (BSZ - 1))) << 11) | dq;
            qmsg[idx]  = pk;
        }
    }
}

// ---- K2: one workgroup per (bucket, segment). 3 native LDS atomics per
// record: two ds_add_u64 (bias-packed) + one u32. Flush = 5 SoA planes.
__global__ __launch_bounds__(1024) void bucket_kernel(
    const unsigned* __restrict__ tails, const unsigned* __restrict__ qmeta,
    const uint2* __restrict__ qmsg, unsigned* __restrict__ partial,
    int nbuk, int seg)
{
    __shared__ unsigned long long accSX[BSZ];   // 16KB
    __shared__ unsigned long long accYZ[BSZ];   // 16KB
    __shared__ unsigned accM[BSZ];              // 8KB
    int wg = blockIdx.x;
    int b = wg / seg, sgi = wg % seg;
    for (int i = threadIdx.x; i < BSZ; i += 1024) {
        accSX[i] = 0ull; accYZ[i] = 0ull; accM[i] = 0u;
    }
    __syncthreads();

    unsigned tail = tails[b * 64];
    if (tail > CAP) tail = CAP;
    unsigned lo = (unsigned)(((unsigned long long)tail * sgi) / seg);
    unsigned hi = (unsigned)(((unsigned long long)tail * (sgi + 1)) / seg);
    size_t base = (size_t)b * CAP;

    for (unsigned q = lo + threadIdx.x; q < hi; q += 1024) {
        unsigned meta = qmeta[base + q];
        uint2 m = qmsg[base + q];
        int local = (int)(meta >> 11);
        int qS = (int)(short)(m.x & 0xFFFFu);
        int qX = (int)(short)(m.x >> 16);
        int qY = (int)(short)(m.y & 0xFFFFu);
        int qZ = (int)(short)(m.y >> 16);
        unsigned long long vSX =
            (((unsigned long long)(unsigned)qX) << 32) | (unsigned)(qS + 65536);
        unsigned long long vYZ =
            (((unsigned long long)(unsigned)qZ) << 32) | (unsigned)(qY + 65536);
        atomicAdd(&accSX[local], vSX);
        atomicAdd(&accYZ[local], vYZ);
        atomicAdd(&accM[local], (1u << 20) | (meta & 2047u));
    }
    __syncthreads();

    unsigned* dst = partial + (size_t)wg * (BSZ * 5);
    for (int i = threadIdx.x; i < BSZ; i += 1024) {
        unsigned long long sx = accSX[i], yz = accYZ[i];
        dst[0*BSZ + i] = (unsigned)sx;
        dst[1*BSZ + i] = (unsigned)(sx >> 32);
        dst[2*BSZ + i] = (unsigned)yz;
        dst[3*BSZ + i] = (unsigned)(yz >> 32);
        dst[4*BSZ + i] = accM[i];
    }
}

// ---- K3: R7 form (best verified). 256-thr blocks, LDS-staged weights,
// 1 node/thread, COMPILE-TIME seg so the partial-decode fully unrolls and
// all loads issue before the staging barrier. R12/R13 closed the scalar-path
// alternative (s_load codegen spills/serializes: 65-84us vs ~50 here).
template<int SEGC>
__global__ __launch_bounds__(256) void mlp_kernel(
    const float* __restrict__ f, const unsigned* __restrict__ partial,
    const float* __restrict__ W0, const float* __restrict__ b0,
    const float* __restrict__ W1, const float* __restrict__ b1,
    const float* __restrict__ W2, const float* __restrict__ b2,
    float* __restrict__ out, int N)
{
    __shared__ float4 sW0t4[64*3];              // W0 transposed, rows of 12
    __shared__ float4 sW1v[64*8];
    __shared__ float4 sW2v[32];
    __shared__ float  sb0[64];
    __shared__ float4 sb1v[8];
    __shared__ float4 sb2v[1];

    int tid = threadIdx.x;
    int n = blockIdx.x * 256 + tid;
    bool vn = (n < N);
    int nc = vn ? n : (N - 1);          // clamped: loads stay in-bounds

    // ---- issue ALL per-node global loads first (fully unrolled,
    // independent) so their latency hides under weight staging.
    int b = nc >> SHIFT;
    int local = nc & (BSZ - 1);
    unsigned pl[SEGC][5];
    #pragma unroll
    for (int s2 = 0; s2 < SEGC; ++s2) {
        const unsigned* p = partial + ((size_t)(b * SEGC + s2)) * (BSZ * 5);
        pl[s2][0] = p[0*BSZ + local];
        pl[s2][1] = p[1*BSZ + local];
        pl[s2][2] = p[2*BSZ + local];
        pl[s2][3] = p[3*BSZ + local];
        pl[s2][4] = p[4*BSZ + local];
    }
    float4 fA = ((const float4*)f)[2*nc];
    float4 fB = ((const float4*)f)[2*nc+1];

    // ---- stage weights to LDS (R2-proven layout/numerics)
    float* w0t = (float*)sW0t4;
    for (int idx = tid; idx < 576; idx += 256) {   // coalesced W0 read
        int k = idx >> 6, i = idx & 63;
        w0t[i * 12 + k] = W0[idx];
    }
    if (tid < 192) {                               // zero the pad lanes
        int i = tid / 3, k = 9 + tid % 3;
        w0t[i * 12 + k] = 0.f;
    }
    { float* p = (float*)sW1v; for (int idx = tid; idx < 2048; idx += 256) p[idx] = W1[idx]; }
    { float* p = (float*)sW2v; if (tid < 128) p[tid] = W2[tid]; }
    if (tid < 64) sb0[tid] = b0[tid];
    { float* p = (float*)sb1v; if (tid < 32) p[tid] = b1[tid]; }
    { float* p = (float*)sb2v; if (tid < 4)  p[tid] = b2[tid]; }
    __syncthreads();

    // ---- fold decode sums (values arrive during staging)
    int S = 0, X = 0, Y = 0, Z = 0, cnt = 0, dqs = 0;
    #pragma unroll
    for (int s2 = 0; s2 < SEGC; ++s2) {
        unsigned m4 = pl[s2][4];
        int c = (int)(m4 >> 20);
        S += (int)pl[s2][0] - (c << 16);
        X += (int)pl[s2][1];
        Y += (int)pl[s2][2] - (c << 16);
        Z += (int)pl[s2][3];
        dqs += (int)(m4 & 0xFFFFFu);
        cnt += c;
    }
    float aS = (float)S * IMQ, ax = (float)X * IMQ;
    float ay = (float)Y * IMQ, az = (float)Z * IMQ;
    float cf = (float)cnt;
    float dsum = (float)dqs * (1.0f / 2047.0f);

    float nrm1 = sqrtf(fA.z*fA.z + fA.w*fA.w + fB.x*fB.x);
    float nrm2 = sqrtf(fB.y*fB.y + fB.z*fB.z + fB.w*fB.w);
    float nv   = sqrtf(ax*ax + ay*ay + az*az);
    float avgd = dsum * fastrcp(cf + 1e-8f);
    float4 p0 = make_float4(fA.x, fA.y, nrm1, nrm2);
    float4 p1 = make_float4(aS, aS, nv, nv);
    float4 p2 = make_float4(avgd, 0.f, 0.f, 0.f);

    // layer1+layer2 interleaved, all LDS reads are b128
    float x1s[32];
    #pragma unroll
    for (int j = 0; j < 8; ++j) {
        float4 bv = sb1v[j];
        x1s[4*j+0] = bv.x; x1s[4*j+1] = bv.y; x1s[4*j+2] = bv.z; x1s[4*j+3] = bv.w;
    }
    #pragma unroll
    for (int i = 0; i < 64; ++i) {
        float4 r0 = sW0t4[i*3+0], r1 = sW0t4[i*3+1], r2 = sW0t4[i*3+2];
        float acc = sb0[i]
            + r0.x*p0.x + r0.y*p0.y + r0.z*p0.z + r0.w*p0.w
            + r1.x*p1.x + r1.y*p1.y + r1.z*p1.z + r1.w*p1.w
            + r2.x*p2.x;
        acc = fmaxf(acc, 0.f);
        #pragma unroll
        for (int j = 0; j < 8; ++j) {
            float4 wv = sW1v[i*8+j];
            x1s[4*j+0] += acc * wv.x;
            x1s[4*j+1] += acc * wv.y;
            x1s[4*j+2] += acc * wv.z;
            x1s[4*j+3] += acc * wv.w;
        }
    }
    #pragma unroll
    for (int j = 0; j < 32; ++j) x1s[j] = fmaxf(x1s[j], 0.f);

    float4 gb = sb2v[0];
    float g0 = gb.x, g1 = gb.y, g2 = gb.z, g3 = gb.w;
    #pragma unroll
    for (int i = 0; i < 32; ++i) {
        float4 wv = sW2v[i];
        g0 += x1s[i] * wv.x;
        g1 += x1s[i] * wv.y;
        g2 += x1s[i] * wv.z;
        g3 += x1s[i] * wv.w;
    }
    if (!vn) return;
    g0 = fastrcp(1.0f + __expf(-g0));
    g1 = fastrcp(1.0f + __expf(-g1));
    g2 = fastrcp(1.0f + __expf(-g2));
    g3 = fastrcp(1.0f + __expf(-g3));

    float* o = out + (size_t)8*n;
    o[0] = fA.x + g0*aS;
    o[1] = fA.y + g1*aS;
    o[2] = fA.z + g2*ax;
    o[3] = fA.w + g2*ay;
    o[4] = fB.x + g2*az;
    o[5] = fB.y + g3*ax;
    o[6] = fB.z + g3*ay;
    o[7] = fB.w + g3*az;
}

// generic fallback (runtime seg) -- only used if seg lands outside 1..10
__global__ __launch_bounds__(256) void mlp_kernel_gen(
    const float* __restrict__ f, const unsigned* __restrict__ partial,
    const float* __restrict__ W0, const float* __restrict__ b0,
    const float* __restrict__ W1, const float* __restrict__ b1,
    const float* __restrict__ W2, const float* __restrict__ b2,
    float* __restrict__ out, int N, int seg)
{
    __shared__ float4 sW0t4[64*3];
    __shared__ float4 sW1v[64*8];
    __shared__ float4 sW2v[32];
    __shared__ float  sb0[64];
    __shared__ float4 sb1v[8];
    __shared__ float4 sb2v[1];

    int tid = threadIdx.x;
    float* w0t = (float*)sW0t4;
    for (int idx = tid; idx < 576; idx += 256) {
        int k = idx >> 6, i = idx & 63;
        w0t[i * 12 + k] = W0[idx];
    }
    if (tid < 192) {
        int i = tid / 3, k = 9 + tid % 3;
        w0t[i * 12 + k] = 0.f;
    }
    { float* p = (float*)sW1v; for (int idx = tid; idx < 2048; idx += 256) p[idx] = W1[idx]; }
    { float* p = (float*)sW2v; if (tid < 128) p[tid] = W2[tid]; }
    if (tid < 64) sb0[tid] = b0[tid];
    { float* p = (float*)sb1v; if (tid < 32) p[tid] = b1[tid]; }
    { float* p = (float*)sb2v; if (tid < 4)  p[tid] = b2[tid]; }
    __syncthreads();

    int n = blockIdx.x * 256 + tid;
    if (n >= N) return;

    int b = n >> SHIFT;
    int local = n & (BSZ - 1);
    int S = 0, X = 0, Y = 0, Z = 0, cnt = 0, dqs = 0;
    for (int s2 = 0; s2 < seg; ++s2) {
        const unsigned* p = partial + ((size_t)(b * seg + s2)) * (BSZ * 5);
        unsigned m4 = p[4*BSZ + local];
        int c = (int)(m4 >> 20);
        S += (int)p[0*BSZ + local] - (c << 16);
        X += (int)p[1*BSZ + local];
        Y += (int)p[2*BSZ + local] - (c << 16);
        Z += (int)p[3*BSZ + local];
        dqs += (int)(m4 & 0xFFFFFu);
        cnt += c;
    }
    float aS = (float)S * IMQ, ax = (float)X * IMQ;
    float ay = (float)Y * IMQ, az = (float)Z * IMQ;
    float cf = (float)cnt;
    float dsum = (float)dqs * (1.0f / 2047.0f);

    float4 fA = ((const float4*)f)[2*n];
    float4 fB = ((const float4*)f)[2*n+1];

    float nrm1 = sqrtf(fA.z*fA.z + fA.w*fA.w + fB.x*fB.x);
    float nrm2 = sqrtf(fB.y*fB.y + fB.z*fB.z + fB.w*fB.w);
    float nv   = sqrtf(ax*ax + ay*ay + az*az);
    float avgd = dsum * fastrcp(cf + 1e-8f);
    float4 p0 = make_float4(fA.x, fA.y, nrm1, nrm2);
    float4 p1 = make_float4(aS, aS, nv, nv);
    float4 p2 = make_float4(avgd, 0.f, 0.f, 0.f);

    float x1s[32];
    #pragma unroll
    for (int j = 0; j < 8; ++j) {
        float4 bv = sb1v[j];
        x1s[4*j+0] = bv.x; x1s[4*j+1] = bv.y; x1s[4*j+2] = bv.z; x1s[4*j+3] = bv.w;
    }
    #pragma unroll
    for (int i = 0; i < 64; ++i) {
        float4 r0 = sW0t4[i*3+0], r1 = sW0t4[i*3+1], r2 = sW0t4[i*3+2];
        float acc = sb0[i]
            + r0.x*p0.x + r0.y*p0.y + r0.z*p0.z + r0.w*p0.w
            + r1.x*p1.x + r1.y*p1.y + r1.z*p1.z + r1.w*p1.w
            + r2.x*p2.x;
        acc = fmaxf(acc, 0.f);
        #pragma unroll
        for (int j = 0; j < 8; ++j) {
            float4 wv = sW1v[i*8+j];
            x1s[4*j+0] += acc * wv.x;
            x1s[4*j+1] += acc * wv.y;
            x1s[4*j+2] += acc * wv.z;
            x1s[4*j+3] += acc * wv.w;
        }
    }
    #pragma unroll
    for (int j = 0; j < 32; ++j) x1s[j] = fmaxf(x1s[j], 0.f);

    float4 gb = sb2v[0];
    float g0 = gb.x, g1 = gb.y, g2 = gb.z, g3 = gb.w;
    #pragma unroll
    for (int i = 0; i < 32; ++i) {
        float4 wv = sW2v[i];
        g0 += x1s[i] * wv.x;
        g1 += x1s[i] * wv.y;
        g2 += x1s[i] * wv.z;
        g3 += x1s[i] * wv.w;
    }
    g0 = fastrcp(1.0f + __expf(-g0));
    g1 = fastrcp(1.0f + __expf(-g1));
    g2 = fastrcp(1.0f + __expf(-g2));
    g3 = fastrcp(1.0f + __expf(-g3));

    float* o = out + (size_t)8*n;
    o[0] = fA.x + g0*aS;
    o[1] = fA.y + g1*aS;
    o[2] = fA.z + g2*ax;
    o[3] = fA.w + g2*ay;
    o[4] = fB.x + g2*az;
    o[5] = fB.y + g3*ax;
    o[6] = fB.z + g3*ay;
    o[7] = fB.w + g3*az;
}

extern "C" void kernel_launch(void* const* d_in, const int* in_sizes, int n_in,
                              void* d_out, int out_size, void* d_ws, size_t ws_size,
                              hipStream_t stream) {
    const int*   ei = (const int*)d_in[0];
    const float* f  = (const float*)d_in[1];
    const float* d  = (const float*)d_in[2];
    const float* a  = (const float*)d_in[3];
    const float* w1 = (const float*)d_in[4];
    const float* w2 = (const float*)d_in[5];
    const float* W0 = (const float*)d_in[6];
    const float* b0 = (const float*)d_in[7];
    const float* W1 = (const float*)d_in[8];
    const float* b1 = (const float*)d_in[9];
    const float* W2 = (const float*)d_in[10];
    const float* b2 = (const float*)d_in[11];
    int E = in_sizes[0] / 2;
    int N = in_sizes[1] / 8;
    int nbuk = (N + BSZ - 1) >> SHIFT;          // 49 for N=100000

    // seg runtime-chosen: target grid = nbuk*seg ~ 512 (2 blocks/CU).
    size_t qn = (size_t)nbuk * CAP;
    size_t fixed = qn * 12 + (size_t)nbuk * 64 * 4;
    size_t per_seg = (size_t)nbuk * BSZ * 5 * 4;
    int segmax = nbuk > 0 ? (512 / nbuk) : 6;   // 10 for nbuk=49
    if (segmax < 1) segmax = 1;
    int seg = 6;
    if (ws_size > fixed + per_seg) {
        size_t m = (ws_size - fixed) / per_seg;
        seg = (int)(m < (size_t)segmax ? m : (size_t)segmax);
        if (seg < 1) seg = 1;
    }

    // workspace layout (bytes):
    //   qmsg    : nbuk*CAP*8        @ 0
    //   qmeta   : nbuk*CAP*4        @ qmsg_end
    //   partial : nbuk*seg*BSZ*5*4  @ qmeta_end
    //   tails   : nbuk*64*4         @ partial_end (zeroed)
    char* w = (char*)d_ws;
    uint2*    qmsg    = (uint2*)w;
    unsigned* qmeta   = (unsigned*)(w + qn * 8);
    unsigned* partial = (unsigned*)(w + qn * 12);
    unsigned* tails   = (unsigned*)(w + qn * 12 + (size_t)seg * per_seg);

    hipMemsetAsync(tails, 0, (size_t)nbuk * 64 * sizeof(unsigned), stream);

    int EB = (E + 1023) / 1024;     // 1563
    route_kernel <<<dim3(EB), dim3(1024), 0, stream>>>(
        ei, f, d, a, w1, w2, tails, qmeta, qmsg, E, nbuk);
    bucket_kernel<<<dim3(nbuk * seg), dim3(1024), 0, stream>>>(
        tails, qmeta, qmsg, partial, nbuk, seg);

    dim3 mg((N + 255) / 256), mb(256);
    switch (seg) {
      case 1:  mlp_kernel<1> <<<mg, mb, 0, stream>>>(f, partial, W0,b0,W1,b1,W2,b2, (float*)d_out, N); break;
      case 2:  mlp_kernel<2> <<<mg, mb, 0, stream>>>(f, partial, W0,b0,W1,b1,W2,b2, (float*)d_out, N); break;
      case 3:  mlp_kernel<3> <<<mg, mb, 0, stream>>>(f, partial, W0,b0,W1,b1,W2,b2, (float*)d_out, N); break;
      case 4:  mlp_kernel<4> <<<mg, mb, 0, stream>>>(f, partial, W0,b0,W1,b1,W2,b2, (float*)d_out, N); break;
      case 5:  mlp_kernel<5> <<<mg, mb, 0, stream>>>(f, partial, W0,b0,W1,b1,W2,b2, (float*)d_out, N); break;
      case 6:  mlp_kernel<6> <<<mg, mb, 0, stream>>>(f, partial, W0,b0,W1,b1,W2,b2, (float*)d_out, N); break;
      case 7:  mlp_kernel<7> <<<mg, mb, 0, stream>>>(f, partial, W0,b0,W1,b1,W2,b2, (float*)d_out, N); break;
      case 8:  mlp_kernel<8> <<<mg, mb, 0, stream>>>(f, partial, W0,b0,W1,b1,W2,b2, (float*)d_out, N); break;
      case 9:  mlp_kernel<9> <<<mg, mb, 0, stream>>>(f, partial, W0,b0,W1,b1,W2,b2, (float*)d_out, N); break;
      case 10: mlp_kernel<10><<<mg, mb, 0, stream>>>(f, partial, W0,b0,W1,b1,W2,b2, (float*)d_out, N); break;
      default:
        mlp_kernel_gen<<<mg, mb, 0, stream>>>(f, partial, W0,b0,W1,b1,W2,b2, (float*)d_out, N, seg);
    }
}